// Round 9
// baseline (467.646 us; speedup 1.0000x reference)
//
#include <hip/hip_runtime.h>
#include <hip/hip_bf16.h>

#define NN 10000
#define TT 8
#define LL 3
#define NGRP 625     // 10000 / 16 exactly

// out layout: ys [N][T][64] = 5,120,000 f32 | h [N][64] = 640,000 | c [N][64]
#define OUT_ELEMS 6400000
#define H_OFF 5120000
#define C_OFF 5760000

typedef __bf16 bf16;
typedef __attribute__((ext_vector_type(8))) __bf16 bf16x8;
typedef __attribute__((ext_vector_type(4))) float f32x4;
typedef __attribute__((ext_vector_type(16))) float f32x16;

// v_rcp_f32 (1 instr) instead of IEEE divide — bf16-grade accuracy (verified r4).
__device__ __forceinline__ float sigf(float x) {
    return __builtin_amdgcn_rcpf(1.0f + __expf(-x));
}
__device__ __forceinline__ float tanhf_(float x) {
    return fmaf(2.0f, __builtin_amdgcn_rcpf(1.0f + __expf(-2.0f * x)), -1.0f);
}

// ---------------------------------------------------------------------------
// prep: repack LSTM weights into bf16 B-fragment order + combine biases;
// zero the per-group completion counters (ws is re-poisoned every launch).
// wts layout (bf16): [l][mat][kh][nt][n16][k32]
// ---------------------------------------------------------------------------
__global__ void prep_kernel(const float* __restrict__ W_ih, const float* __restrict__ W_hh,
                            const float* __restrict__ b_ih, const float* __restrict__ b_hh,
                            bf16* __restrict__ wts, float* __restrict__ bias,
                            unsigned* __restrict__ cnt) {
    int id = blockIdx.x * 256 + threadIdx.x;
    if (id < NGRP) cnt[id] = 0u;
    if (id < LL * 2 * 256 * 64) {
        int col = id & 63;
        int row = (id >> 6) & 255;
        int mat = (id >> 14) & 1;
        int l = id >> 15;
        const float* src = mat ? W_hh : W_ih;
        float w = src[(l * 256 + row) * 64 + col];
        int kh = col >> 5, nt = row >> 4, nn = row & 15, kk = col & 31;
        wts[((((l * 2 + mat) * 2 + kh) * 16 + nt) * 16 + nn) * 32 + kk] = (bf16)w;
    } else if (id < LL * 2 * 256 * 64 + LL * 256) {
        int id2 = id - LL * 2 * 256 * 64;
        bias[id2] = b_ih[id2] + b_hh[id2];
    }
}

// ---------------------------------------------------------------------------
// fused_split: grid = 3*625; block = (level, 16 nodes); 256 thr (4 waves).
// conv: 32x32x16 MFMA (M = 2 nodes x 16 nbrs, K = C = 16 exact) -> LDS feat.
// Chunk loop MUST stay unroll 1 (full unroll pipelines ~272 VGPRs of loads ->
// scratch spill -> 480 MB HBM; measured r5).
// lstm: wave wv owns gate tiles {wv,4+wv,8+wv,12+wv}; 16 weight frags in
// registers; 16 MFMAs + 1 barrier per step; rcp cell.
// Epilogue: write level slab; last-arriving block of the group (split-K
// counter pattern; one atomicAdd per block, NO data atomics — r8 showed
// 19M CAS ops cost 251 MB / +133 us) merges the 3 slabs into out.
// ---------------------------------------------------------------------------
__global__ __launch_bounds__(256, 4) void fused_split_kernel(
    const float* __restrict__ X, const int* __restrict__ As,
    const float* __restrict__ conv_w, const float* __restrict__ conv_b,
    const bf16* __restrict__ wts, const float* __restrict__ bias,
    float* __restrict__ slabs, float* __restrict__ out,
    unsigned* __restrict__ cnt) {
    __shared__ __align__(16) bf16 featL[TT][16][72];   // 18.4 KB
    __shared__ __align__(16) bf16 hlds[2][16][72];     // 4.6 KB
    __shared__ unsigned s_done;

    const int tid = threadIdx.x;
    const int l = blockIdx.x % 3;
    const int grp = blockIdx.x / 3;
    const int node0 = grp * 16;

    const int lane = tid & 63;
    const int wv = tid >> 6;        // 0..3
    const int c16 = lane & 15;
    const int q = lane >> 4;
    const int m = lane & 31;        // conv: A row = (node-in-pair)<<4 | nbr
    const int hh = lane >> 5;       // conv: k-half
    const int ch0 = hh * 8;
    const int nsub = m >> 4;
    const int kn = m & 15;

    // ================= conv stage =================
    bf16x8 B0, B1;
    {
        const float* w0 = conv_w + ((l * 64 + m) * 16 + ch0);
        f32x4 a = *(const f32x4*)w0, b = *(const f32x4*)(w0 + 4);
        const float* w1 = conv_w + ((l * 64 + 32 + m) * 16 + ch0);
        f32x4 c = *(const f32x4*)w1, d = *(const f32x4*)(w1 + 4);
#pragma unroll
        for (int j = 0; j < 4; ++j) {
            B0[j] = (bf16)a[j]; B0[4 + j] = (bf16)b[j];
            B1[j] = (bf16)c[j]; B1[4 + j] = (bf16)d[j];
        }
    }
    const float cb0 = conv_b[l * 64 + m];
    const float cb1 = conv_b[l * 64 + 32 + m];

#pragma unroll 1
    for (int c = 0; c < 4; ++c) {
        const int pc = 2 * wv + (c & 1);
        const int t0 = (c >> 1) * 4;
        const int gn = node0 + 2 * pc + nsub;

        int aidx[4];
#pragma unroll
        for (int j = 0; j < 4; ++j)
            aidx[j] = As[((long)(l * 8 + t0 + j) * NN + gn) * 16 + kn];
        f32x4 sv[4][2], gv[4][2];
#pragma unroll
        for (int j = 0; j < 4; ++j) {
            const float* sp = X + ((gn * 8 + t0 + j) * 16 + ch0);
            sv[j][0] = *(const f32x4*)sp;
            sv[j][1] = *(const f32x4*)(sp + 4);
        }
#pragma unroll
        for (int j = 0; j < 4; ++j) {
            const float* gp = X + (((long)aidx[j] * 8 + t0 + j) * 16 + ch0);
            gv[j][0] = *(const f32x4*)gp;
            gv[j][1] = *(const f32x4*)(gp + 4);
        }

#pragma unroll
        for (int j = 0; j < 4; ++j) {
            bf16x8 af;
#pragma unroll
            for (int k = 0; k < 4; ++k) {
                af[k]     = (bf16)(gv[j][0][k] - sv[j][0][k]);
                af[4 + k] = (bf16)(gv[j][1][k] - sv[j][1][k]);
            }
            f32x16 D0, D1;
#pragma unroll
            for (int k = 0; k < 16; ++k) { D0[k] = 0.0f; D1[k] = 0.0f; }
            D0 = __builtin_amdgcn_mfma_f32_32x32x16_bf16(af, B0, D0, 0, 0, 0);
            D1 = __builtin_amdgcn_mfma_f32_32x32x16_bf16(af, B1, D1, 0, 0, 0);

            float v00 = D0[0], v01 = D1[0], v10 = D0[8], v11 = D1[8];
#pragma unroll
            for (int k = 1; k < 8; ++k) {
                v00 = fmaxf(v00, D0[k]);     v01 = fmaxf(v01, D1[k]);
                v10 = fmaxf(v10, D0[8 + k]); v11 = fmaxf(v11, D1[8 + k]);
            }
            v00 = fmaxf(v00, __shfl_xor(v00, 32));
            v01 = fmaxf(v01, __shfl_xor(v01, 32));
            v10 = fmaxf(v10, __shfl_xor(v10, 32));
            v11 = fmaxf(v11, __shfl_xor(v11, 32));

            const float sA = hh ? v10 : v00;   // cols [0,32)
            const float sB = hh ? v11 : v01;   // cols [32,64)
            featL[t0 + j][2 * pc + hh][m]      = (bf16)(sA + cb0);
            featL[t0 + j][2 * pc + hh][32 + m] = (bf16)(sB + cb1);
        }
    }

    // ================= LSTM weights (registers) =================
    const bf16* wb = wts + l * 32768;
    const int fo = c16 * 32 + q * 8;
    bf16x8 Bx0[4], Bx1[4], Bh0[4], Bh1[4];
    float brg[4];
#pragma unroll
    for (int g = 0; g < 4; ++g) {
        const int nt = 4 * g + wv;
        Bx0[g] = *(const bf16x8*)(wb + (0 * 16 + nt) * 512 + fo);
        Bx1[g] = *(const bf16x8*)(wb + (1 * 16 + nt) * 512 + fo);
        Bh0[g] = *(const bf16x8*)(wb + (2 * 16 + nt) * 512 + fo);
        Bh1[g] = *(const bf16x8*)(wb + (3 * 16 + nt) * 512 + fo);
        brg[g] = bias[l * 256 + nt * 16 + c16];
    }
    float c_r[4];
#pragma unroll
    for (int r = 0; r < 4; ++r) c_r[r] = 0.0f;

    float ymax[TT][4], hfin[4], cfin[4];

    // ================= 8 recurrent steps =================
#pragma unroll
    for (int t = 0; t < TT; ++t) {
        __syncthreads();  // t=0: featL ready; t>0: h(t-1) visible

        bf16x8 ax0 = *(const bf16x8*)&featL[t][c16][q * 8];
        bf16x8 ax1 = *(const bf16x8*)&featL[t][c16][32 + q * 8];
        bf16x8 ah0, ah1;
        if (t > 0) {
            ah0 = *(const bf16x8*)&hlds[(t + 1) & 1][c16][q * 8];
            ah1 = *(const bf16x8*)&hlds[(t + 1) & 1][c16][32 + q * 8];
        }

        f32x4 acc[4];
#pragma unroll
        for (int g = 0; g < 4; ++g) {
            float b = brg[g];
            acc[g] = (f32x4){b, b, b, b};
            acc[g] = __builtin_amdgcn_mfma_f32_16x16x32_bf16(ax0, Bx0[g], acc[g], 0, 0, 0);
            acc[g] = __builtin_amdgcn_mfma_f32_16x16x32_bf16(ax1, Bx1[g], acc[g], 0, 0, 0);
            if (t > 0) {
                acc[g] = __builtin_amdgcn_mfma_f32_16x16x32_bf16(ah0, Bh0[g], acc[g], 0, 0, 0);
                acc[g] = __builtin_amdgcn_mfma_f32_16x16x32_bf16(ah1, Bh1[g], acc[g], 0, 0, 0);
            }
        }

        // cell: lane holds nodes q*4+r, hidden col wv*16+c16
#pragma unroll
        for (int r = 0; r < 4; ++r) {
            float iv = acc[0][r], fv = acc[1][r], gg = acc[2][r], ov = acc[3][r];
            float c = sigf(fv) * c_r[r] + sigf(iv) * tanhf_(gg);
            c_r[r] = c;
            float h = sigf(ov) * tanhf_(c);
            hlds[t & 1][q * 4 + r][wv * 16 + c16] = (bf16)h;
            ymax[t][r] = h;
            if (t == TT - 1) { hfin[r] = h; cfin[r] = c; }
        }
    }

    // ================= write this level's slab =================
    float* slab = slabs + (long)l * OUT_ELEMS;
    const int col = wv * 16 + c16;
#pragma unroll
    for (int t = 0; t < TT; ++t)
#pragma unroll
        for (int r = 0; r < 4; ++r)
            slab[((long)(node0 + q * 4 + r) * 8 + t) * 64 + col] = ymax[t][r];
#pragma unroll
    for (int r = 0; r < 4; ++r) {
        slab[H_OFF + (long)(node0 + q * 4 + r) * 64 + col] = hfin[r];
        slab[C_OFF + (long)(node0 + q * 4 + r) * 64 + col] = cfin[r];
    }

    // ================= last-block merge (split-K counter pattern) ==========
    __syncthreads();  // all slab stores drained (compiler emits vmcnt(0))
    if (tid == 0)
        s_done = __hip_atomic_fetch_add(&cnt[grp], 1u, __ATOMIC_ACQ_REL,
                                        __HIP_MEMORY_SCOPE_AGENT);
    __syncthreads();
    if (s_done == 2u) {       // we arrived last: both other levels' slabs done
        __threadfence();      // acquire: invalidate stale cached lines
        const float* s0 = slabs;
        const float* s1 = slabs + (long)OUT_ELEMS;
        const float* s2 = slabs + 2L * OUT_ELEMS;
        {   // ys: 16 nodes x 512 floats, contiguous
            const long base = (long)node0 * 512;
            const f32x4* a0 = (const f32x4*)(s0 + base);
            const f32x4* a1 = (const f32x4*)(s1 + base);
            const f32x4* a2 = (const f32x4*)(s2 + base);
            f32x4* o = (f32x4*)(out + base);
#pragma unroll
            for (int i = 0; i < 8; ++i) {
                const int idx = i * 256 + tid;
                f32x4 a = a0[idx], b = a1[idx], c = a2[idx], d;
#pragma unroll
                for (int k = 0; k < 4; ++k) d[k] = fmaxf(fmaxf(a[k], b[k]), c[k]);
                o[idx] = d;
            }
        }
        {   // h and c: 1024 floats each = 256 f32x4 each (one per thread)
            const long bh = (long)H_OFF + (long)node0 * 64;
            const long bc = (long)C_OFF + (long)node0 * 64;
            f32x4 a, b, c, d;
            a = ((const f32x4*)(s0 + bh))[tid];
            b = ((const f32x4*)(s1 + bh))[tid];
            c = ((const f32x4*)(s2 + bh))[tid];
#pragma unroll
            for (int k = 0; k < 4; ++k) d[k] = fmaxf(fmaxf(a[k], b[k]), c[k]);
            ((f32x4*)(out + bh))[tid] = d;
            a = ((const f32x4*)(s0 + bc))[tid];
            b = ((const f32x4*)(s1 + bc))[tid];
            c = ((const f32x4*)(s2 + bc))[tid];
#pragma unroll
            for (int k = 0; k < 4; ++k) d[k] = fmaxf(fmaxf(a[k], b[k]), c[k]);
            ((f32x4*)(out + bc))[tid] = d;
        }
    }
}

extern "C" void kernel_launch(void* const* d_in, const int* in_sizes, int n_in,
                              void* d_out, int out_size, void* d_ws, size_t ws_size,
                              hipStream_t stream) {
    const float* X = (const float*)d_in[0];
    const int* As = (const int*)d_in[1];
    const float* conv_w = (const float*)d_in[4];
    const float* conv_b = (const float*)d_in[5];
    const float* W_ih = (const float*)d_in[6];
    const float* W_hh = (const float*)d_in[7];
    const float* b_ih = (const float*)d_in[8];
    const float* b_hh = (const float*)d_in[9];
    float* out = (float*)d_out;

    char* ws = (char*)d_ws;
    const size_t slabs_bytes = (size_t)3 * OUT_ELEMS * 4;   // 76.8 MB (ws proven >= this in r7)
    float* slabs = (float*)ws;
    bf16* wts = (bf16*)(ws + slabs_bytes);                  // 196,608 B
    float* bias = (float*)(ws + slabs_bytes + 196608);      // 3,072 B
    unsigned* cnt = (unsigned*)(ws + slabs_bytes + 196608 + 4096);  // 2,500 B

    hipLaunchKernelGGL(prep_kernel, dim3(387), dim3(256), 0, stream,
                       W_ih, W_hh, b_ih, b_hh, wts, bias, cnt);
    hipLaunchKernelGGL(fused_split_kernel, dim3(3 * NGRP), dim3(256), 0, stream,
                       X, As, conv_w, conv_b, wts, bias, slabs, out, cnt);
}

// Round 10
// 454.711 us; speedup vs baseline: 1.0284x; 1.0284x over previous
//
#include <hip/hip_runtime.h>
#include <hip/hip_bf16.h>

#define NN 10000
#define TT 8
#define LL 3
#define NGRP 625     // 10000 / 16 exactly

// out layout: ys [N][T][64] = 5,120,000 f32 | h [N][64] = 640,000 | c [N][64]
#define OUT_ELEMS 6400000
#define H_OFF 5120000
#define C_OFF 5760000

typedef __bf16 bf16;
typedef __attribute__((ext_vector_type(8))) __bf16 bf16x8;
typedef __attribute__((ext_vector_type(4))) float f32x4;
typedef __attribute__((ext_vector_type(16))) float f32x16;

// v_rcp_f32 (1 instr) instead of IEEE divide — bf16-grade accuracy (verified r4).
__device__ __forceinline__ float sigf(float x) {
    return __builtin_amdgcn_rcpf(1.0f + __expf(-x));
}
__device__ __forceinline__ float tanhf_(float x) {
    return fmaf(2.0f, __builtin_amdgcn_rcpf(1.0f + __expf(-2.0f * x)), -1.0f);
}

// ---------------------------------------------------------------------------
// prep: repack LSTM weights into bf16 B-fragment order + combine biases;
// zero the per-group completion counters (ws is re-poisoned every launch).
// wts layout (bf16): [l][mat][kh][nt][n16][k32]
// ---------------------------------------------------------------------------
__global__ void prep_kernel(const float* __restrict__ W_ih, const float* __restrict__ W_hh,
                            const float* __restrict__ b_ih, const float* __restrict__ b_hh,
                            bf16* __restrict__ wts, float* __restrict__ bias,
                            unsigned* __restrict__ cnt) {
    int id = blockIdx.x * 256 + threadIdx.x;
    if (id < NGRP) cnt[id] = 0u;
    if (id < LL * 2 * 256 * 64) {
        int col = id & 63;
        int row = (id >> 6) & 255;
        int mat = (id >> 14) & 1;
        int l = id >> 15;
        const float* src = mat ? W_hh : W_ih;
        float w = src[(l * 256 + row) * 64 + col];
        int kh = col >> 5, nt = row >> 4, nn = row & 15, kk = col & 31;
        wts[((((l * 2 + mat) * 2 + kh) * 16 + nt) * 16 + nn) * 32 + kk] = (bf16)w;
    } else if (id < LL * 2 * 256 * 64 + LL * 256) {
        int id2 = id - LL * 2 * 256 * 64;
        bias[id2] = b_ih[id2] + b_hh[id2];
    }
}

// ---------------------------------------------------------------------------
// fused_split: grid = 3*625; block = (level, 16 nodes); 256 thr (4 waves).
// __launch_bounds__(256,3): the proven no-spill config. r9 measured that
// (256,4)'s 128-VGPR cap forces recurrent-loop scratch spills (438 us).
// ys is streamed to the slab inside the step loop (frees the 32-VGPR ymax
// array; if allocation lands <=128 the HW gives 4 blocks/CU for free).
// conv: 32x32x16 MFMA (M = 2 nodes x 16 nbrs, K = C = 16 exact) -> LDS feat.
// Chunk loop MUST stay unroll 1 (r5: full unroll -> ~272 VGPRs in flight ->
// spills -> 480 MB HBM).
// lstm: wave wv owns gate tiles {wv,4+wv,8+wv,12+wv}; 16 weight frags in
// registers; 16 MFMAs + 1 barrier per step; rcp cell.
// Epilogue: split-K counter merge — ONE atomicAdd per block (r8: per-element
// CAS-fmax cost 251 MB / +133 us); last-arriving block max-merges the slabs.
// ---------------------------------------------------------------------------
__global__ __launch_bounds__(256, 3) void fused_split_kernel(
    const float* __restrict__ X, const int* __restrict__ As,
    const float* __restrict__ conv_w, const float* __restrict__ conv_b,
    const bf16* __restrict__ wts, const float* __restrict__ bias,
    float* __restrict__ slabs, float* __restrict__ out,
    unsigned* __restrict__ cnt) {
    __shared__ __align__(16) bf16 featL[TT][16][72];   // 18.4 KB
    __shared__ __align__(16) bf16 hlds[2][16][72];     // 4.6 KB
    __shared__ unsigned s_done;

    const int tid = threadIdx.x;
    const int l = blockIdx.x % 3;
    const int grp = blockIdx.x / 3;
    const int node0 = grp * 16;

    const int lane = tid & 63;
    const int wv = tid >> 6;        // 0..3
    const int c16 = lane & 15;
    const int q = lane >> 4;
    const int m = lane & 31;        // conv: A row = (node-in-pair)<<4 | nbr
    const int hh = lane >> 5;       // conv: k-half
    const int ch0 = hh * 8;
    const int nsub = m >> 4;
    const int kn = m & 15;

    // ================= conv stage =================
    bf16x8 B0, B1;
    {
        const float* w0 = conv_w + ((l * 64 + m) * 16 + ch0);
        f32x4 a = *(const f32x4*)w0, b = *(const f32x4*)(w0 + 4);
        const float* w1 = conv_w + ((l * 64 + 32 + m) * 16 + ch0);
        f32x4 c = *(const f32x4*)w1, d = *(const f32x4*)(w1 + 4);
#pragma unroll
        for (int j = 0; j < 4; ++j) {
            B0[j] = (bf16)a[j]; B0[4 + j] = (bf16)b[j];
            B1[j] = (bf16)c[j]; B1[4 + j] = (bf16)d[j];
        }
    }
    const float cb0 = conv_b[l * 64 + m];
    const float cb1 = conv_b[l * 64 + 32 + m];

#pragma unroll 1
    for (int c = 0; c < 4; ++c) {
        const int pc = 2 * wv + (c & 1);
        const int t0 = (c >> 1) * 4;
        const int gn = node0 + 2 * pc + nsub;

        int aidx[4];
#pragma unroll
        for (int j = 0; j < 4; ++j)
            aidx[j] = As[((long)(l * 8 + t0 + j) * NN + gn) * 16 + kn];
        f32x4 sv[4][2], gv[4][2];
#pragma unroll
        for (int j = 0; j < 4; ++j) {
            const float* sp = X + ((gn * 8 + t0 + j) * 16 + ch0);
            sv[j][0] = *(const f32x4*)sp;
            sv[j][1] = *(const f32x4*)(sp + 4);
        }
#pragma unroll
        for (int j = 0; j < 4; ++j) {
            const float* gp = X + (((long)aidx[j] * 8 + t0 + j) * 16 + ch0);
            gv[j][0] = *(const f32x4*)gp;
            gv[j][1] = *(const f32x4*)(gp + 4);
        }

#pragma unroll
        for (int j = 0; j < 4; ++j) {
            bf16x8 af;
#pragma unroll
            for (int k = 0; k < 4; ++k) {
                af[k]     = (bf16)(gv[j][0][k] - sv[j][0][k]);
                af[4 + k] = (bf16)(gv[j][1][k] - sv[j][1][k]);
            }
            f32x16 D0, D1;
#pragma unroll
            for (int k = 0; k < 16; ++k) { D0[k] = 0.0f; D1[k] = 0.0f; }
            D0 = __builtin_amdgcn_mfma_f32_32x32x16_bf16(af, B0, D0, 0, 0, 0);
            D1 = __builtin_amdgcn_mfma_f32_32x32x16_bf16(af, B1, D1, 0, 0, 0);

            float v00 = D0[0], v01 = D1[0], v10 = D0[8], v11 = D1[8];
#pragma unroll
            for (int k = 1; k < 8; ++k) {
                v00 = fmaxf(v00, D0[k]);     v01 = fmaxf(v01, D1[k]);
                v10 = fmaxf(v10, D0[8 + k]); v11 = fmaxf(v11, D1[8 + k]);
            }
            v00 = fmaxf(v00, __shfl_xor(v00, 32));
            v01 = fmaxf(v01, __shfl_xor(v01, 32));
            v10 = fmaxf(v10, __shfl_xor(v10, 32));
            v11 = fmaxf(v11, __shfl_xor(v11, 32));

            const float sA = hh ? v10 : v00;   // cols [0,32)
            const float sB = hh ? v11 : v01;   // cols [32,64)
            featL[t0 + j][2 * pc + hh][m]      = (bf16)(sA + cb0);
            featL[t0 + j][2 * pc + hh][32 + m] = (bf16)(sB + cb1);
        }
    }

    // ================= LSTM weights (registers) =================
    const bf16* wb = wts + l * 32768;
    const int fo = c16 * 32 + q * 8;
    bf16x8 Bx0[4], Bx1[4], Bh0[4], Bh1[4];
    float brg[4];
#pragma unroll
    for (int g = 0; g < 4; ++g) {
        const int nt = 4 * g + wv;
        Bx0[g] = *(const bf16x8*)(wb + (0 * 16 + nt) * 512 + fo);
        Bx1[g] = *(const bf16x8*)(wb + (1 * 16 + nt) * 512 + fo);
        Bh0[g] = *(const bf16x8*)(wb + (2 * 16 + nt) * 512 + fo);
        Bh1[g] = *(const bf16x8*)(wb + (3 * 16 + nt) * 512 + fo);
        brg[g] = bias[l * 256 + nt * 16 + c16];
    }
    float c_r[4];
#pragma unroll
    for (int r = 0; r < 4; ++r) c_r[r] = 0.0f;

    float hfin[4], cfin[4];
    float* slab = slabs + (long)l * OUT_ELEMS;
    const int col = wv * 16 + c16;

    // ================= 8 recurrent steps (ys streamed to slab) ============
#pragma unroll
    for (int t = 0; t < TT; ++t) {
        __syncthreads();  // t=0: featL ready; t>0: h(t-1) visible

        bf16x8 ax0 = *(const bf16x8*)&featL[t][c16][q * 8];
        bf16x8 ax1 = *(const bf16x8*)&featL[t][c16][32 + q * 8];
        bf16x8 ah0, ah1;
        if (t > 0) {
            ah0 = *(const bf16x8*)&hlds[(t + 1) & 1][c16][q * 8];
            ah1 = *(const bf16x8*)&hlds[(t + 1) & 1][c16][32 + q * 8];
        }

        f32x4 acc[4];
#pragma unroll
        for (int g = 0; g < 4; ++g) {
            float b = brg[g];
            acc[g] = (f32x4){b, b, b, b};
            acc[g] = __builtin_amdgcn_mfma_f32_16x16x32_bf16(ax0, Bx0[g], acc[g], 0, 0, 0);
            acc[g] = __builtin_amdgcn_mfma_f32_16x16x32_bf16(ax1, Bx1[g], acc[g], 0, 0, 0);
            if (t > 0) {
                acc[g] = __builtin_amdgcn_mfma_f32_16x16x32_bf16(ah0, Bh0[g], acc[g], 0, 0, 0);
                acc[g] = __builtin_amdgcn_mfma_f32_16x16x32_bf16(ah1, Bh1[g], acc[g], 0, 0, 0);
            }
        }

        // cell: lane holds nodes q*4+r, hidden col wv*16+c16
#pragma unroll
        for (int r = 0; r < 4; ++r) {
            float iv = acc[0][r], fv = acc[1][r], gg = acc[2][r], ov = acc[3][r];
            float c = sigf(fv) * c_r[r] + sigf(iv) * tanhf_(gg);
            c_r[r] = c;
            float h = sigf(ov) * tanhf_(c);
            hlds[t & 1][q * 4 + r][wv * 16 + c16] = (bf16)h;
            slab[((long)(node0 + q * 4 + r) * 8 + t) * 64 + col] = h;
            if (t == TT - 1) { hfin[r] = h; cfin[r] = c; }
        }
    }

    // ================= finish slab (h, c) =================
#pragma unroll
    for (int r = 0; r < 4; ++r) {
        slab[H_OFF + (long)(node0 + q * 4 + r) * 64 + col] = hfin[r];
        slab[C_OFF + (long)(node0 + q * 4 + r) * 64 + col] = cfin[r];
    }

    // ================= last-block merge (split-K counter pattern) ==========
    __syncthreads();  // all slab stores drained (compiler emits vmcnt(0))
    if (tid == 0)
        s_done = __hip_atomic_fetch_add(&cnt[grp], 1u, __ATOMIC_ACQ_REL,
                                        __HIP_MEMORY_SCOPE_AGENT);
    __syncthreads();
    if (s_done == 2u) {       // we arrived last: both other levels' slabs done
        __threadfence();      // acquire: invalidate stale cached lines
        const float* s0 = slabs;
        const float* s1 = slabs + (long)OUT_ELEMS;
        const float* s2 = slabs + 2L * OUT_ELEMS;
        {   // ys: 16 nodes x 512 floats, contiguous
            const long base = (long)node0 * 512;
            const f32x4* a0 = (const f32x4*)(s0 + base);
            const f32x4* a1 = (const f32x4*)(s1 + base);
            const f32x4* a2 = (const f32x4*)(s2 + base);
            f32x4* o = (f32x4*)(out + base);
#pragma unroll
            for (int i = 0; i < 8; ++i) {
                const int idx = i * 256 + tid;
                f32x4 a = a0[idx], b = a1[idx], c = a2[idx], d;
#pragma unroll
                for (int k = 0; k < 4; ++k) d[k] = fmaxf(fmaxf(a[k], b[k]), c[k]);
                o[idx] = d;
            }
        }
        {   // h and c: 1024 floats each = 256 f32x4 each (one per thread)
            const long bh = (long)H_OFF + (long)node0 * 64;
            const long bc = (long)C_OFF + (long)node0 * 64;
            f32x4 a, b, c, d;
            a = ((const f32x4*)(s0 + bh))[tid];
            b = ((const f32x4*)(s1 + bh))[tid];
            c = ((const f32x4*)(s2 + bh))[tid];
#pragma unroll
            for (int k = 0; k < 4; ++k) d[k] = fmaxf(fmaxf(a[k], b[k]), c[k]);
            ((f32x4*)(out + bh))[tid] = d;
            a = ((const f32x4*)(s0 + bc))[tid];
            b = ((const f32x4*)(s1 + bc))[tid];
            c = ((const f32x4*)(s2 + bc))[tid];
#pragma unroll
            for (int k = 0; k < 4; ++k) d[k] = fmaxf(fmaxf(a[k], b[k]), c[k]);
            ((f32x4*)(out + bc))[tid] = d;
        }
    }
}

extern "C" void kernel_launch(void* const* d_in, const int* in_sizes, int n_in,
                              void* d_out, int out_size, void* d_ws, size_t ws_size,
                              hipStream_t stream) {
    const float* X = (const float*)d_in[0];
    const int* As = (const int*)d_in[1];
    const float* conv_w = (const float*)d_in[4];
    const float* conv_b = (const float*)d_in[5];
    const float* W_ih = (const float*)d_in[6];
    const float* W_hh = (const float*)d_in[7];
    const float* b_ih = (const float*)d_in[8];
    const float* b_hh = (const float*)d_in[9];
    float* out = (float*)d_out;

    char* ws = (char*)d_ws;
    const size_t slabs_bytes = (size_t)3 * OUT_ELEMS * 4;   // 76.8 MB
    float* slabs = (float*)ws;
    bf16* wts = (bf16*)(ws + slabs_bytes);                  // 196,608 B
    float* bias = (float*)(ws + slabs_bytes + 196608);      // 3,072 B
    unsigned* cnt = (unsigned*)(ws + slabs_bytes + 196608 + 4096);  // 2,500 B

    hipLaunchKernelGGL(prep_kernel, dim3(387), dim3(256), 0, stream,
                       W_ih, W_hh, b_ih, b_hh, wts, bias, cnt);
    hipLaunchKernelGGL(fused_split_kernel, dim3(3 * NGRP), dim3(256), 0, stream,
                       X, As, conv_w, conv_b, wts, bias, slabs, out, cnt);
}